// Round 5
// baseline (1260.594 us; speedup 1.0000x reference)
//
#include <hip/hip_runtime.h>
#include <hip/hip_bf16.h>

// ---------------------------------------------------------------------------
// GINEConv x2 + mean-pool + 3 heads.  f32 pipeline (correctness anchor).
// KEY FACTS: float inputs = f32, OUTPUT = f32.  Int width runtime-detected.
//
// R5: W float4 in LDS, 8 edges/wave, readlane broadcast (995 -> 423us).
// R6: occupancy push: no effect (423 -> 411).
// R7: per-node CSR: REGRESSED (561) - dependent ES->load chain, no pipeline.
// R8: sw pipelining (depth-1 prefetch + hoisted gathers): 411 -> 352us.
//     VALUBusy 87% is CU-ORed (~37%/SIMD) => still latency-bound.
// R9 (this round):
//   - FLAT dst-sorted edge walk: chunks of 8 sequential CSR slots (no
//     per-node padding), dst piecewise-constant -> run-length-coalesced
//     atomics flushed at run boundaries (~5x fewer atomics, writes
//     400->~80MB, ascending addresses).  Depth-2 index pipeline.
//   - Fused per-layer MLP: t=relu(A@W1+b1); out=relu(t@W2+b2) in regs.
//     Traffic + W-staging halve, 4 dispatches -> 2.
// ---------------------------------------------------------------------------

typedef __bf16 bf16_t;

#define N_NODES   50000
#define N_EDGES   800000
#define N_GRAPHS  512
#define HID       128
#define EIN       64
#define PNODES    16
#define SCAN_BLK  1024
#define NCHUNK    49            // ceil(50000/1024)

#define RL(v, l)  __int_as_float(__builtin_amdgcn_readlane(__float_as_int(v), (l)))
#define RLI(v, l) __builtin_amdgcn_readlane((v), (l))

__device__ __forceinline__ float ldf(const void* p, size_t i, int f32m) {
    return f32m ? ((const float*)p)[i] : (float)((const bf16_t*)p)[i];
}
__device__ __forceinline__ int ldi(const void* p, size_t i, int i64m) {
    return i64m ? (int)((const long long*)p)[i] : ((const int*)p)[i];
}

// flags[0]=1 if floats are f32; flags[1]=1 if ints are i64.
__global__ void k_detect(const unsigned short* __restrict__ xw,
                         const unsigned int*   __restrict__ eiw,
                         int* __restrict__ flags)
{
    if (threadIdx.x == 0 && blockIdx.x == 0) {
        int sane = 0;
        for (int i = 0; i < 256; ++i) {
            int e = (xw[i] >> 7) & 0xFF;
            if (e >= 100 && e <= 150) ++sane;
        }
        flags[0] = (sane < 220) ? 1 : 0;
        int nzhigh = 0;
        for (int i = 0; i < 256; ++i)
            if (eiw[2*i + 1] != 0) ++nzhigh;
        flags[1] = (nzhigh == 0) ? 1 : 0;
    }
}

__global__ void k_cvt4(const void* __restrict__ x, float* __restrict__ dst,
                       const int* __restrict__ flags) {
    const int f32m = flags[0];
    size_t i = (size_t)blockIdx.x * 256 + threadIdx.x;
    if (f32m) {
        ((float4*)dst)[i] = ((const float4*)x)[i];
    } else {
        const bf16_t* s = (const bf16_t*)x;
        float4 v;
        v.x = (float)s[4*i+0]; v.y = (float)s[4*i+1];
        v.z = (float)s[4*i+2]; v.w = (float)s[4*i+3];
        ((float4*)dst)[i] = v;
    }
}

// ---------------- CSR build (once; shared by both edge layers) -------------
__global__ void k_hist(const void* __restrict__ ei, int* __restrict__ CNT,
                       const int* __restrict__ flags)
{
    const int i64m = flags[1];
    int e = blockIdx.x * 256 + threadIdx.x;
    int d = ldi(ei, (size_t)N_EDGES + e, i64m);
    atomicAdd(&CNT[d], 1);
}

__global__ __launch_bounds__(SCAN_BLK) void k_scanA(const int* __restrict__ CNT,
                                                    int* __restrict__ OFF,
                                                    int* __restrict__ PS)
{
    __shared__ int tmp[SCAN_BLK];
    const int t = threadIdx.x;
    const int i = blockIdx.x * SCAN_BLK + t;
    const int v = (i < N_NODES) ? CNT[i] : 0;
    tmp[t] = v;
    __syncthreads();
    for (int off = 1; off < SCAN_BLK; off <<= 1) {
        int u = (t >= off) ? tmp[t - off] : 0;
        __syncthreads();
        tmp[t] += u;
        __syncthreads();
    }
    if (i < N_NODES) OFF[i] = tmp[t] - v;
    if (t == SCAN_BLK - 1) PS[blockIdx.x] = tmp[t];
}

__global__ void k_scanB(int* __restrict__ PS)
{
    const int lane = threadIdx.x;                // 64 threads
    const int v0 = (lane < NCHUNK) ? PS[lane] : 0;
    int v = v0;
#pragma unroll
    for (int off = 1; off < 64; off <<= 1) {
        int u = __shfl_up(v, off, 64);
        if (lane >= off) v += u;
    }
    if (lane < NCHUNK) PS[lane] = v - v0;
}

__global__ void k_scanC(int* __restrict__ OFF, const int* __restrict__ PS,
                        int* __restrict__ CUR)
{
    int i = blockIdx.x * 256 + threadIdx.x;
    if (i < N_NODES) {
        int o = OFF[i] + PS[i >> 10];
        OFF[i] = o;
        CUR[i] = o;
    }
}

// CSR layout: one int base; [0..E) = eid, [E..2E) = src, [2E..3E) = dst
__global__ void k_scatter(const void* __restrict__ ei, int* __restrict__ CUR,
                          int* __restrict__ CSR, const int* __restrict__ flags)
{
    const int i64m = flags[1];
    int e = blockIdx.x * 256 + threadIdx.x;
    int s = ldi(ei, e, i64m);
    int d = ldi(ei, (size_t)N_EDGES + e, i64m);
    int p = atomicAdd(&CUR[d], 1);
    CSR[p]              = e;
    CSR[N_EDGES + p]    = s;
    CSR[2*N_EDGES + p]  = d;
}

// ---------------------------------------------------------------------------
// Flat dst-sorted edge kernel.  Chunks of 8 sequential CSR slots.
//   e = ea[eid]@W + eb (readlane broadcast, W float4 LDS); m = relu(x_src+e);
//   run-length-coalesced atomicAdd into ag[dst] (dst sorted -> few flushes).
// Pipeline: idx depth-2 (vvA=cur, vvB=next), ea rows depth-1 (avA/avB).
// ---------------------------------------------------------------------------
__global__ __launch_bounds__(512) void k_edge_s(
        const void* __restrict__ Xg, int xg_ws,
        const int*  __restrict__ CSR,
        const void* __restrict__ ea,
        const void* __restrict__ ew,
        const void* __restrict__ eb,
        float*      __restrict__ ag,
        const int*  __restrict__ flags)
{
    __shared__ float4 Wq[16 * 128];               // 32 KB
    __shared__ float  ebs[HID];
    const int f32m = flags[0];
    const int xgf  = xg_ws ? 1 : f32m;

    for (int i = threadIdx.x; i < 16 * 128; i += 512) {
        int k4 = i >> 7, c = i & 127;
        float4 w;
        w.x = ldf(ew, (size_t)(4*k4+0)*HID + c, f32m);
        w.y = ldf(ew, (size_t)(4*k4+1)*HID + c, f32m);
        w.z = ldf(ew, (size_t)(4*k4+2)*HID + c, f32m);
        w.w = ldf(ew, (size_t)(4*k4+3)*HID + c, f32m);
        Wq[i] = w;
    }
    for (int i = threadIdx.x; i < HID; i += 512) ebs[i] = ldf(eb, i, f32m);
    __syncthreads();

    const int lane = threadIdx.x & 63;
    const int wid  = (blockIdx.x * 512 + threadIdx.x) >> 6;
    const int nw   = gridDim.x * 8;
    const int ngrp = N_EDGES / 8;                 // 100000 exact
    const float eb0 = ebs[lane], eb1 = ebs[64 + lane];

    // lanes 0-7: eid, 8-15: src, 16-23: dst of the chunk
    auto LOADIDX = [&](int p0) -> int {
        int v = 0;
        if (lane < 24) v = CSR[(size_t)(lane >> 3) * N_EDGES + p0 + (lane & 7)];
        return v;
    };
    auto LOADAV = [&](int vv, float* av) {
#pragma unroll
        for (int i = 0; i < 8; ++i) {
            int eid = RLI(vv, i);
            av[i] = ldf(ea, (size_t)eid * EIN + lane, f32m);
        }
    };

    int g = wid;
    if (g < ngrp) {
        float avA[8];
        int vvA = LOADIDX(g * 8);
        LOADAV(vvA, avA);
        int gB = g + nw;
        int vvB = (gB < ngrp) ? LOADIDX(gB * 8) : 0;

        while (true) {
            const bool hasB = (gB < ngrp);
            // prefetch ea rows for next chunk (indices already here)
            float avB[8];
            if (hasB) LOADAV(vvB, avB);
            // prefetch indices two chunks ahead
            const int gC = gB + nw;
            int vvC = (hasB && gC < ngrp) ? LOADIDX(gC * 8) : 0;

            // current chunk: src/dst via readlane, issue x-gathers early
            int src[8], dst[8];
#pragma unroll
            for (int i = 0; i < 8; ++i) {
                src[i] = RLI(vvA, 8 + i);
                dst[i] = RLI(vvA, 16 + i);
            }
            float x0[8], x1[8];
#pragma unroll
            for (int i = 0; i < 8; ++i) {
                x0[i] = ldf(Xg, (size_t)src[i] * HID + lane,      xgf);
                x1[i] = ldf(Xg, (size_t)src[i] * HID + 64 + lane, xgf);
            }

            float acc0[8], acc1[8];
#pragma unroll
            for (int i = 0; i < 8; ++i) { acc0[i] = 0.f; acc1[i] = 0.f; }

#pragma unroll 4
            for (int k4 = 0; k4 < 16; ++k4) {
                float4 w0 = Wq[k4 * 128 + lane];
                float4 w1 = Wq[k4 * 128 + 64 + lane];
#pragma unroll
                for (int i = 0; i < 8; ++i) {
                    float a0 = RL(avA[i], 4*k4+0);
                    float a1 = RL(avA[i], 4*k4+1);
                    float a2 = RL(avA[i], 4*k4+2);
                    float a3 = RL(avA[i], 4*k4+3);
                    acc0[i] = fmaf(a3, w0.w, fmaf(a2, w0.z, fmaf(a1, w0.y, fmaf(a0, w0.x, acc0[i]))));
                    acc1[i] = fmaf(a3, w1.w, fmaf(a2, w1.z, fmaf(a1, w1.y, fmaf(a0, w1.x, acc1[i]))));
                }
            }

            // run-length-coalesced epilogue (dst sorted, SGPR compares)
            float s0 = 0.f, s1 = 0.f;
#pragma unroll
            for (int i = 0; i < 8; ++i) {
                float v0 = fmaxf(x0[i] + acc0[i] + eb0, 0.f);
                float v1 = fmaxf(x1[i] + acc1[i] + eb1, 0.f);
                s0 += v0; s1 += v1;
                if (i == 7 || dst[i + 1] != dst[i]) {
                    unsafeAtomicAdd(ag + (size_t)dst[i] * HID + lane,      s0);
                    unsafeAtomicAdd(ag + (size_t)dst[i] * HID + 64 + lane, s1);
                    s0 = 0.f; s1 = 0.f;
                }
            }

            if (!hasB) break;
            g = gB; gB = gC;
            vvA = vvB; vvB = vvC;
#pragma unroll
            for (int i = 0; i < 8; ++i) avA[i] = avB[i];
        }
    }
}

// ---------------------------------------------------------------------------
// Fused node MLP pair: Out[n] = relu( relu(A[n]@W1+b1) @ W2 + b2 ).
// 8 nodes per wave; W1,W2 as float4 in LDS (128KB -> 1 block/CU, 16 waves).
// In-place safe (wave only writes its own chunk).  Out2: optional dup store.
// ---------------------------------------------------------------------------
__global__ __launch_bounds__(1024) void k_mlp2(
        const float* __restrict__ A,
        const void*  __restrict__ W1, const void* __restrict__ b1,
        const void*  __restrict__ W2, const void* __restrict__ b2,
        float*       __restrict__ Out,
        float*       __restrict__ Out2,
        const int*   __restrict__ flags)
{
    __shared__ float4 W1q[32 * 128];              // 64 KB
    __shared__ float4 W2q[32 * 128];              // 64 KB
    const int f32m = flags[0];
    for (int i = threadIdx.x; i < 32 * 128; i += 1024) {
        int k4 = i >> 7, c = i & 127;
        float4 w;
        w.x = ldf(W1, (size_t)(4*k4+0)*HID + c, f32m);
        w.y = ldf(W1, (size_t)(4*k4+1)*HID + c, f32m);
        w.z = ldf(W1, (size_t)(4*k4+2)*HID + c, f32m);
        w.w = ldf(W1, (size_t)(4*k4+3)*HID + c, f32m);
        W1q[i] = w;
        w.x = ldf(W2, (size_t)(4*k4+0)*HID + c, f32m);
        w.y = ldf(W2, (size_t)(4*k4+1)*HID + c, f32m);
        w.z = ldf(W2, (size_t)(4*k4+2)*HID + c, f32m);
        w.w = ldf(W2, (size_t)(4*k4+3)*HID + c, f32m);
        W2q[i] = w;
    }
    __syncthreads();

    const int lane = threadIdx.x & 63;
    const int wid  = (blockIdx.x * 1024 + threadIdx.x) >> 6;
    const int nw   = gridDim.x * 16;
    const float c10 = ldf(b1, lane,      f32m);
    const float c11 = ldf(b1, 64 + lane, f32m);
    const float c20 = ldf(b2, lane,      f32m);
    const float c21 = ldf(b2, 64 + lane, f32m);
    const int ngrp = N_NODES / 8;                 // 6250 exact

    for (int g = wid; g < ngrp; g += nw) {
        const int n0 = g * 8;
        float alo[8], ahi[8], t0[8], t1[8];
#pragma unroll
        for (int i = 0; i < 8; ++i) {
            alo[i] = A[(size_t)(n0+i) * HID + lane];
            ahi[i] = A[(size_t)(n0+i) * HID + 64 + lane];
            t0[i] = c10; t1[i] = c11;
        }
        // ---- MLP1: t = relu(A@W1 + b1) ----
#pragma unroll 4
        for (int k4 = 0; k4 < 16; ++k4) {
            float4 w0 = W1q[k4 * 128 + lane];
            float4 w1 = W1q[k4 * 128 + 64 + lane];
#pragma unroll
            for (int i = 0; i < 8; ++i) {
                float a0 = RL(alo[i], 4*k4+0);
                float a1 = RL(alo[i], 4*k4+1);
                float a2 = RL(alo[i], 4*k4+2);
                float a3 = RL(alo[i], 4*k4+3);
                t0[i] = fmaf(a3, w0.w, fmaf(a2, w0.z, fmaf(a1, w0.y, fmaf(a0, w0.x, t0[i]))));
                t1[i] = fmaf(a3, w1.w, fmaf(a2, w1.z, fmaf(a1, w1.y, fmaf(a0, w1.x, t1[i]))));
            }
        }
#pragma unroll 4
        for (int k4 = 16; k4 < 32; ++k4) {
            float4 w0 = W1q[k4 * 128 + lane];
            float4 w1 = W1q[k4 * 128 + 64 + lane];
#pragma unroll
            for (int i = 0; i < 8; ++i) {
                float a0 = RL(ahi[i], 4*k4+0 - 64);
                float a1 = RL(ahi[i], 4*k4+1 - 64);
                float a2 = RL(ahi[i], 4*k4+2 - 64);
                float a3 = RL(ahi[i], 4*k4+3 - 64);
                t0[i] = fmaf(a3, w0.w, fmaf(a2, w0.z, fmaf(a1, w0.y, fmaf(a0, w0.x, t0[i]))));
                t1[i] = fmaf(a3, w1.w, fmaf(a2, w1.z, fmaf(a1, w1.y, fmaf(a0, w1.x, t1[i]))));
            }
        }
#pragma unroll
        for (int i = 0; i < 8; ++i) {
            t0[i] = fmaxf(t0[i], 0.f);
            t1[i] = fmaxf(t1[i], 0.f);
        }
        // ---- MLP2: out = relu(t@W2 + b2) ----
        float o0[8], o1[8];
#pragma unroll
        for (int i = 0; i < 8; ++i) { o0[i] = c20; o1[i] = c21; }
#pragma unroll 4
        for (int k4 = 0; k4 < 16; ++k4) {
            float4 w0 = W2q[k4 * 128 + lane];
            float4 w1 = W2q[k4 * 128 + 64 + lane];
#pragma unroll
            for (int i = 0; i < 8; ++i) {
                float a0 = RL(t0[i], 4*k4+0);
                float a1 = RL(t0[i], 4*k4+1);
                float a2 = RL(t0[i], 4*k4+2);
                float a3 = RL(t0[i], 4*k4+3);
                o0[i] = fmaf(a3, w0.w, fmaf(a2, w0.z, fmaf(a1, w0.y, fmaf(a0, w0.x, o0[i]))));
                o1[i] = fmaf(a3, w1.w, fmaf(a2, w1.z, fmaf(a1, w1.y, fmaf(a0, w1.x, o1[i]))));
            }
        }
#pragma unroll 4
        for (int k4 = 16; k4 < 32; ++k4) {
            float4 w0 = W2q[k4 * 128 + lane];
            float4 w1 = W2q[k4 * 128 + 64 + lane];
#pragma unroll
            for (int i = 0; i < 8; ++i) {
                float a0 = RL(t1[i], 4*k4+0 - 64);
                float a1 = RL(t1[i], 4*k4+1 - 64);
                float a2 = RL(t1[i], 4*k4+2 - 64);
                float a3 = RL(t1[i], 4*k4+3 - 64);
                o0[i] = fmaf(a3, w0.w, fmaf(a2, w0.z, fmaf(a1, w0.y, fmaf(a0, w0.x, o0[i]))));
                o1[i] = fmaf(a3, w1.w, fmaf(a2, w1.z, fmaf(a1, w1.y, fmaf(a0, w1.x, o1[i]))));
            }
        }
#pragma unroll
        for (int i = 0; i < 8; ++i) {
            float v0 = fmaxf(o0[i], 0.f);
            float v1 = fmaxf(o1[i], 0.f);
            Out[(size_t)(n0+i) * HID + lane]      = v0;
            Out[(size_t)(n0+i) * HID + 64 + lane] = v1;
            if (Out2) {
                Out2[(size_t)(n0+i) * HID + lane]      = v0;
                Out2[(size_t)(n0+i) * HID + 64 + lane] = v1;
            }
        }
    }
}

// ---------------------------------------------------------------------------
// Pool: batch SORTED -> run-length accumulate, flush at boundaries.
// ---------------------------------------------------------------------------
__global__ void k_pool_s(const float* __restrict__ X, const void* __restrict__ batch,
                         float* __restrict__ GS, float* __restrict__ GC,
                         const int* __restrict__ flags)
{
    const int i64m = flags[1];
    const int c  = threadIdx.x;                   // 0..127 (2 waves)
    const int tl = threadIdx.x & 63;
    const int n0 = blockIdx.x * PNODES;

    int bv = (tl < PNODES) ? ldi(batch, n0 + tl, i64m) : 0;

    int bprev = RLI(bv, 0);
    float acc = 0.f;
    int   cnt = 0;
#pragma unroll
    for (int j = 0; j < PNODES; ++j) {
        int b = RLI(bv, j);
        if (b != bprev) {
            unsafeAtomicAdd(&GS[(size_t)bprev * HID + c], acc);
            if (c == 0) unsafeAtomicAdd(&GC[bprev], (float)cnt);
            acc = 0.f; cnt = 0; bprev = b;
        }
        acc += X[(size_t)(n0 + j) * HID + c];
        ++cnt;
    }
    unsafeAtomicAdd(&GS[(size_t)bprev * HID + c], acc);
    if (c == 0) unsafeAtomicAdd(&GC[bprev], (float)cnt);
}

// Head: one wave per graph; OUTPUT IS FLOAT32.
__global__ void k_head(const float* __restrict__ GS, const float* __restrict__ GC,
                       const void* __restrict__ fcw, const void* __restrict__ fcb,
                       const void* __restrict__ hSw, const void* __restrict__ hSb,
                       const void* __restrict__ hPw, const void* __restrict__ hPb,
                       const void* __restrict__ hNw, const void* __restrict__ hNb,
                       float* __restrict__ out, const int* __restrict__ flags)
{
    const int f32m = flags[0];
    const int g = blockIdx.x;
    const int lane = threadIdx.x;                 // 64 threads
    const float inv = 1.f / fmaxf(GC[g], 1.f);
    const float g0 = GS[(size_t)g * HID + lane]      * inv;
    const float g1 = GS[(size_t)g * HID + 64 + lane] * inv;

    float acc = 0.f;
    for (int k = 0; k < 64; ++k) {
        float gk = __shfl(g0, k, 64);
        acc += gk * ldf(fcw, k * 64 + lane, f32m);
    }
    for (int k = 0; k < 64; ++k) {
        float gk = __shfl(g1, k, 64);
        acc += gk * ldf(fcw, (64 + k) * 64 + lane, f32m);
    }
    float s = fmaxf(acc + ldf(fcb, lane, f32m), 0.f);

    float pS = s * ldf(hSw, lane, f32m);
    float pP = s * ldf(hPw, lane, f32m);
    float pN = s * ldf(hNw, lane, f32m);
#pragma unroll
    for (int off = 32; off; off >>= 1) {
        pS += __shfl_down(pS, off, 64);
        pP += __shfl_down(pP, off, 64);
        pN += __shfl_down(pN, off, 64);
    }
    if (lane == 0) {
        out[g]                = pS + ldf(hSb, 0, f32m);
        out[N_GRAPHS + g]     = pP + ldf(hPb, 0, f32m);
        out[2 * N_GRAPHS + g] = pN + ldf(hNb, 0, f32m);
    }
}

extern "C" void kernel_launch(void* const* d_in, const int* in_sizes, int n_in,
                              void* d_out, int out_size, void* d_ws, size_t ws_size,
                              hipStream_t stream)
{
    const void* x     = d_in[0];
    const void* ei    = d_in[1];
    const void* ea    = d_in[2];
    const void* batch = d_in[3];
    const void* e1w = d_in[4],  *e1b = d_in[5];
    const void* n1w1= d_in[6],  *n1b1= d_in[7];
    const void* n1w2= d_in[8],  *n1b2= d_in[9];
    const void* e2w = d_in[10], *e2b = d_in[11];
    const void* n2w1= d_in[12], *n2b1= d_in[13];
    const void* n2w2= d_in[14], *n2b2= d_in[15];
    const void* fcw = d_in[16], *fcb = d_in[17];
    const void* hSw = d_in[18], *hSb = d_in[19];
    const void* hPw = d_in[20], *hPb = d_in[21];
    const void* hNw = d_in[22], *hNb = d_in[23];

    float* B1  = (float*)d_ws;                         // 6.4M f32
    float* B2  = B1 + (size_t)N_NODES * HID;           // 6.4M f32
    float* GS  = B2 + (size_t)N_NODES * HID;           // 512*128 f32
    float* GC  = GS + (size_t)N_GRAPHS * HID;          // 512 f32
    int*   FL  = (int*)(GC + N_GRAPHS);                // 4 ints
    int*   PS  = FL + 4;                               // 64 ints
    int*   OFF = PS + 64;                              // 50000
    int*   CNT = OFF + N_NODES;                        // 50000
    int*   CUR = CNT + N_NODES;                        // 50000
    int*   CSR = CUR + N_NODES;                        // 3*800000 ints (9.6MB)
    // total ~62 MB

    k_detect<<<1, 64, 0, stream>>>((const unsigned short*)x, (const unsigned int*)ei, FL);
    hipMemsetAsync(GS, 0, (N_GRAPHS * HID + N_GRAPHS) * sizeof(float), stream);
    hipMemsetAsync(CNT, 0, N_NODES * sizeof(int), stream);

    // ---- CSR build (once) ----
    k_hist   <<<N_EDGES / 256, 256, 0, stream>>>(ei, CNT, FL);
    k_scanA  <<<NCHUNK, SCAN_BLK, 0, stream>>>(CNT, OFF, PS);
    k_scanB  <<<1, 64, 0, stream>>>(PS);
    k_scanC  <<<(N_NODES + 255) / 256, 256, 0, stream>>>(OFF, PS, CUR);
    k_scatter<<<N_EDGES / 256, 256, 0, stream>>>(ei, CUR, CSR, FL);

    const int NV4_BLKS = (N_NODES * HID / 4) / 256;    // 6250 (exact)

    // ---- Layer 1 ----
    k_cvt4  <<<NV4_BLKS, 256, 0, stream>>>(x, B1, FL);
    k_edge_s<<<2048, 512, 0, stream>>>(x, 0, CSR, ea, e1w, e1b, B1, FL);
    k_mlp2  <<<256, 1024, 0, stream>>>(B1, n1w1, n1b1, n1w2, n1b2, B1, B2, FL);

    // ---- Layer 2 ----
    k_edge_s<<<2048, 512, 0, stream>>>(B1, 1, CSR, ea, e2w, e2b, B2, FL);
    k_mlp2  <<<256, 1024, 0, stream>>>(B2, n2w1, n2b1, n2w2, n2b2, B2, nullptr, FL);

    // ---- Pool + heads ----
    k_pool_s<<<N_NODES / PNODES, 128, 0, stream>>>(B2, batch, GS, GC, FL);
    k_head  <<<N_GRAPHS, 64, 0, stream>>>(GS, GC, fcw, fcb, hSw, hSb, hPw, hPb, hNw, hNb,
                                          (float*)d_out, FL);
}